// Round 16
// baseline (1033.572 us; speedup 1.0000x reference)
//
#include <hip/hip_runtime.h>
#include <hip/hip_fp16.h>
#include <math.h>

typedef unsigned short u16;

#define NN 2560
#define EE 327680
#define HC 256         // H*C
#define FIN 62
#define CAP 240        // per-node global bucket capacity (max degree+1 ~ 181)
#define NCH 32         // edge chunks
#define CHSZ (EE / NCH)  // 10240
#define PCAP 32        // per-(node,chunk) LDS bucket capacity
#define GRID 1024      // persistent grid: 4 blocks/CU x 256 CUs

__device__ __forceinline__ float lrelu(float x) { return x >= 0.f ? x : 0.2f * x; }
__device__ __forceinline__ float ldh(const __half* p, int i) { return __half2float(p[i]); }

// grid-wide barrier: per-phase counter, device-scope atomics (XCD-coherent)
__device__ __forceinline__ void gsync(int* bar, int k) {
  __syncthreads();
  if (threadIdx.x == 0) {
    __threadfence();                 // release: flush this block's writes
    atomicAdd(&bar[k], 1);
    while (atomicAdd(&bar[k], 0) < GRID) { __builtin_amdgcn_s_sleep(1); }
    __threadfence();                 // acquire: invalidate stale cache lines
  }
  __syncthreads();
}

__global__ __launch_bounds__(256, 4)
void k_mega(const float* __restrict__ x, const int* __restrict__ src,
            const int* __restrict__ dst, const float* __restrict__ pos,
            const float* __restrict__ mask,
            const float* __restrict__ W1, const float* __restrict__ as1,
            const float* __restrict__ ad1, const float* __restrict__ b1,
            const float* __restrict__ g1, const float* __restrict__ be1,
            const float* __restrict__ W2, const float* __restrict__ as2,
            const float* __restrict__ ad2, const float* __restrict__ b2,
            const float* __restrict__ g2, const float* __restrict__ be2,
            const float* __restrict__ Wf, const float* __restrict__ bfv,
            float* __restrict__ out,
            float* __restrict__ agg, float* __restrict__ asb, float* __restrict__ adb,
            float* __restrict__ mu, float* __restrict__ rinv,
            int* __restrict__ cntd, u16* __restrict__ esrcB,
            __half* __restrict__ o, __half* __restrict__ h, int* __restrict__ bar) {
  __shared__ alignas(16) char smem[7424];
  int bid = blockIdx.x;
  int t = threadIdx.x;

  // ---- P0: init (self-loop seeds, zero agg) ----
  {
    int g = bid * 256 + t;
    if (g < NN) {
      cntd[g] = 1;
      esrcB[g * CAP] = (u16)g;
      agg[2 * g] = 0.f;
      agg[2 * g + 1] = 0.f;
    }
  }
  gsync(bar, 0);

  // ---- P1: binning + fused edge-feature aggregation (1280 items) ----
  {
    u16 (*bufD)[PCAP] = (u16(*)[PCAP])smem;            // 4096
    int* cD    = (int*)(smem + 4096);                   // 256
    int* baseD = (int*)(smem + 4352);                   // 256
    float* aggD = (float*)(smem + 4608);                // 256
    float* aggA = (float*)(smem + 4864);                // 256
    for (int it = bid; it < NCH * (NN / 64); it += GRID) {
      int c = it & (NCH - 1);
      int r = it >> 5;   // NCH == 32
      if (t < 64) { cD[t] = 0; aggD[t] = 0.f; aggA[t] = 0.f; }
      __syncthreads();
      int e0 = c * CHSZ;
      const int4* s4p = (const int4*)(src + e0);
      const int4* d4p = (const int4*)(dst + e0);
      for (int i = t; i < CHSZ / 4; i += 256) {
        int4 s4 = s4p[i];
        int4 d4 = d4p[i];
        int ss[4] = {s4.x, s4.y, s4.z, s4.w};
        int dd[4] = {d4.x, d4.y, d4.z, d4.w};
#pragma unroll
        for (int k = 0; k < 4; ++k) {
          int s = ss[k], d = dd[k];
          if ((d >> 6) == r) {
            int p = atomicAdd(&cD[d & 63], 1);
            if (p < PCAP) {
              bufD[d & 63][p] = (u16)s;
            } else {  // guaranteed-correct spill (disjoint vs batch reserve)
              int idx = atomicAdd(&cntd[d], 1);
              esrcB[d * CAP + idx] = (u16)s;
            }
          }
          if ((s >> 6) == r) {
            float2 psv = ((const float2*)pos)[s];
            float2 pdv = ((const float2*)pos)[d];
            float dx = pdv.x - psv.x, dy = pdv.y - psv.y;
            atomicAdd(&aggD[s & 63], sqrtf(dx * dx + dy * dy));
            atomicAdd(&aggA[s & 63], atan2f(dy, dx));
          }
        }
      }
      __syncthreads();
      if (t < 64) baseD[t] = atomicAdd(&cntd[r * 64 + t], min(cD[t], PCAP));
      __syncthreads();
      for (int idx = t; idx < 64 * PCAP; idx += 256) {
        int n = idx >> 5;   // PCAP == 32
        int i = idx & 31;
        if (i < min(cD[n], PCAP)) esrcB[(r * 64 + n) * CAP + baseD[n] + i] = bufD[n][i];
      }
      if (t < 64) {
        atomicAdd(&agg[2 * (r * 64 + t)], aggD[t]);
        atomicAdd(&agg[2 * (r * 64 + t) + 1], aggA[t]);
      }
      __syncthreads();
    }
  }
  gsync(bar, 1);

  // ---- P2: gemm1 (640 items x 4 nodes), fused concat + alpha epilogue ----
  {
    float (*xrow)[64] = (float(*)[64])smem;   // 1024
    for (int it = bid; it < NN / 4; it += GRID) {
      int n0 = it * 4;
      int m0 = t >> 6, i0 = t & 63;
      xrow[m0][i0] = (i0 < FIN) ? x[(n0 + m0) * FIN + i0] : agg[(n0 + m0) * 2 + (i0 - FIN)];
      __syncthreads();
      float a0 = 0.f, a1 = 0.f, a2 = 0.f, a3 = 0.f;
#pragma unroll 8
      for (int k = 0; k < 64; ++k) {
        float w = W1[k * HC + t];
        a0 += xrow[0][k] * w; a1 += xrow[1][k] * w;
        a2 += xrow[2][k] * w; a3 += xrow[3][k] * w;
      }
      h[(n0 + 0) * HC + t] = __float2half(a0);
      h[(n0 + 1) * HC + t] = __float2half(a1);
      h[(n0 + 2) * HC + t] = __float2half(a2);
      h[(n0 + 3) * HC + t] = __float2half(a3);
      float accs[4] = {a0, a1, a2, a3};
      int hh = t >> 6, lane = t & 63;
      float vs = as1[t], vdd = ad1[t];
#pragma unroll
      for (int m = 0; m < 4; ++m) {
        float p1 = accs[m] * vs;
        float p2 = accs[m] * vdd;
        for (int oo = 32; oo > 0; oo >>= 1) {
          p1 += __shfl_down(p1, oo);
          p2 += __shfl_down(p2, oo);
        }
        if (lane == 0) {
          asb[(n0 + m) * 4 + hh] = p1;
          adb[(n0 + m) * 4 + hh] = p2;
        }
      }
      __syncthreads();
    }
  }
  gsync(bar, 2);

  // ---- P3: agg layer 1 (2560 items), half2 gather ----
  {
    float (*eE)[256] = (float(*)[256])smem;             // 4096
    int* sS = (int*)(smem + 4096);                      // 1024
    float2* accbuf = (float2*)(smem + 5120);            // 2048
    float (*wred)[4] = (float(*)[4])(smem + 7168);      // 64
    for (int it = bid; it < NN; it += GRID) {
      int n = it;
      int cnt = min(cntd[n], CAP);
      float ad0 = adb[n * 4 + 0], ad1v = adb[n * 4 + 1];
      float ad2v = adb[n * 4 + 2], ad3 = adb[n * 4 + 3];
      float e0 = 0.f, e1 = 0.f, e2 = 0.f, e3 = 0.f;
      int s = 0;
      if (t < cnt) {
        s = (int)esrcB[n * CAP + t];
        e0 = expf(lrelu(asb[s * 4 + 0] + ad0));
        e1 = expf(lrelu(asb[s * 4 + 1] + ad1v));
        e2 = expf(lrelu(asb[s * 4 + 2] + ad2v));
        e3 = expf(lrelu(asb[s * 4 + 3] + ad3));
      }
      eE[0][t] = e0; eE[1][t] = e1; eE[2][t] = e2; eE[3][t] = e3;
      sS[t] = s;
      float d0 = e0, d1 = e1, d2 = e2, d3 = e3;
      for (int oo = 32; oo > 0; oo >>= 1) {
        d0 += __shfl_down(d0, oo);
        d1 += __shfl_down(d1, oo);
        d2 += __shfl_down(d2, oo);
        d3 += __shfl_down(d3, oo);
      }
      if ((t & 63) == 0) {
        wred[t >> 6][0] = d0; wred[t >> 6][1] = d1;
        wred[t >> 6][2] = d2; wred[t >> 6][3] = d3;
      }
      __syncthreads();
      int grp = t >> 7, c2 = t & 127, hh = c2 >> 5;
      const __half2* H2 = (const __half2*)h;
      float accx = 0.f, accy = 0.f;
      for (int j = grp; j < cnt; j += 2) {
        float w = eE[hh][j];
        float2 f = __half22float2(H2[sS[j] * 128 + c2]);
        accx += w * f.x; accy += w * f.y;
      }
      accbuf[t] = make_float2(accx, accy);
      __syncthreads();
      if (t < 128) {
        float2 a0 = accbuf[t], a1 = accbuf[t + 128];
        int hh2 = t >> 5;
        float den = wred[0][hh2] + wred[1][hh2] + wred[2][hh2] + wred[3][hh2] + 1e-16f;
        __half2 r;
        r.x = __float2half((a0.x + a1.x) / den + b1[2 * t]);
        r.y = __float2half((a0.y + a1.y) / den + b1[2 * t + 1]);
        ((__half2*)o)[n * 128 + t] = r;
      }
      __syncthreads();
    }
  }
  gsync(bar, 3);

  // ---- P4: BN1 stats (256 items) ----
  {
    float* rs = (float*)smem;
    float* rq = (float*)(smem + 1024);
    if (bid < HC) {
      int f = bid;
      float sv = 0.f, sq = 0.f;
      for (int n = t; n < NN; n += 256) {
        float v = ldh(o, n * HC + f);
        sv += v;
        sq += v * v;
      }
      rs[t] = sv; rq[t] = sq;
      __syncthreads();
      for (int oo = 128; oo > 0; oo >>= 1) {
        if (t < oo) { rs[t] += rs[t + oo]; rq[t] += rq[t + oo]; }
        __syncthreads();
      }
      if (t == 0) {
        float m = rs[0] / NN;
        float var = rq[0] / NN - m * m;
        mu[f] = m;
        rinv[f] = rsqrtf(var + 1e-5f);
      }
    }
  }
  gsync(bar, 4);

  // ---- P5: gemm2 (640 items), fused BN1+ReLU + alpha epilogue ----
  {
    float (*xrow)[256] = (float(*)[256])smem;   // 4096
    for (int it = bid; it < NN / 4; it += GRID) {
      int n0 = it * 4;
      float bmu = mu[t], brv = rinv[t], bg = g1[t], bb = be1[t];
#pragma unroll
      for (int m = 0; m < 4; ++m)
        xrow[m][t] = fmaxf((ldh(o, (n0 + m) * HC + t) - bmu) * brv * bg + bb, 0.f);
      __syncthreads();
      float a0 = 0.f, a1 = 0.f, a2 = 0.f, a3 = 0.f;
#pragma unroll 4
      for (int k = 0; k < 256; ++k) {
        float w = W2[k * HC + t];
        a0 += xrow[0][k] * w; a1 += xrow[1][k] * w;
        a2 += xrow[2][k] * w; a3 += xrow[3][k] * w;
      }
      h[(n0 + 0) * HC + t] = __float2half(a0);
      h[(n0 + 1) * HC + t] = __float2half(a1);
      h[(n0 + 2) * HC + t] = __float2half(a2);
      h[(n0 + 3) * HC + t] = __float2half(a3);
      float accs[4] = {a0, a1, a2, a3};
      int hh = t >> 6, lane = t & 63;
      float vs = as2[t], vdd = ad2[t];
#pragma unroll
      for (int m = 0; m < 4; ++m) {
        float p1 = accs[m] * vs;
        float p2 = accs[m] * vdd;
        for (int oo = 32; oo > 0; oo >>= 1) {
          p1 += __shfl_down(p1, oo);
          p2 += __shfl_down(p2, oo);
        }
        if (lane == 0) {
          asb[(n0 + m) * 4 + hh] = p1;
          adb[(n0 + m) * 4 + hh] = p2;
        }
      }
      __syncthreads();
    }
  }
  gsync(bar, 5);

  // ---- P6: agg layer 2 (2560 items), half2 gather ----
  {
    float (*eE)[256] = (float(*)[256])smem;
    int* sS = (int*)(smem + 4096);
    float2* accbuf = (float2*)(smem + 5120);
    float (*wred)[4] = (float(*)[4])(smem + 7168);
    for (int it = bid; it < NN; it += GRID) {
      int n = it;
      int cnt = min(cntd[n], CAP);
      float ad0 = adb[n * 4 + 0], ad1v = adb[n * 4 + 1];
      float ad2v = adb[n * 4 + 2], ad3 = adb[n * 4 + 3];
      float e0 = 0.f, e1 = 0.f, e2 = 0.f, e3 = 0.f;
      int s = 0;
      if (t < cnt) {
        s = (int)esrcB[n * CAP + t];
        e0 = expf(lrelu(asb[s * 4 + 0] + ad0));
        e1 = expf(lrelu(asb[s * 4 + 1] + ad1v));
        e2 = expf(lrelu(asb[s * 4 + 2] + ad2v));
        e3 = expf(lrelu(asb[s * 4 + 3] + ad3));
      }
      eE[0][t] = e0; eE[1][t] = e1; eE[2][t] = e2; eE[3][t] = e3;
      sS[t] = s;
      float d0 = e0, d1 = e1, d2 = e2, d3 = e3;
      for (int oo = 32; oo > 0; oo >>= 1) {
        d0 += __shfl_down(d0, oo);
        d1 += __shfl_down(d1, oo);
        d2 += __shfl_down(d2, oo);
        d3 += __shfl_down(d3, oo);
      }
      if ((t & 63) == 0) {
        wred[t >> 6][0] = d0; wred[t >> 6][1] = d1;
        wred[t >> 6][2] = d2; wred[t >> 6][3] = d3;
      }
      __syncthreads();
      int grp = t >> 7, c2 = t & 127, hh = c2 >> 5;
      const __half2* H2 = (const __half2*)h;
      float accx = 0.f, accy = 0.f;
      for (int j = grp; j < cnt; j += 2) {
        float w = eE[hh][j];
        float2 f = __half22float2(H2[sS[j] * 128 + c2]);
        accx += w * f.x; accy += w * f.y;
      }
      accbuf[t] = make_float2(accx, accy);
      __syncthreads();
      if (t < 128) {
        float2 a0 = accbuf[t], a1 = accbuf[t + 128];
        int hh2 = t >> 5;
        float den = wred[0][hh2] + wred[1][hh2] + wred[2][hh2] + wred[3][hh2] + 1e-16f;
        __half2 r;
        r.x = __float2half((a0.x + a1.x) / den + b2[2 * t]);
        r.y = __float2half((a0.y + a1.y) / den + b2[2 * t + 1]);
        ((__half2*)o)[n * 128 + t] = r;
      }
      __syncthreads();
    }
  }
  gsync(bar, 6);

  // ---- P7: BN2 stats ----
  {
    float* rs = (float*)smem;
    float* rq = (float*)(smem + 1024);
    if (bid < HC) {
      int f = bid;
      float sv = 0.f, sq = 0.f;
      for (int n = t; n < NN; n += 256) {
        float v = ldh(o, n * HC + f);
        sv += v;
        sq += v * v;
      }
      rs[t] = sv; rq[t] = sq;
      __syncthreads();
      for (int oo = 128; oo > 0; oo >>= 1) {
        if (t < oo) { rs[t] += rs[t + oo]; rq[t] += rq[t + oo]; }
        __syncthreads();
      }
      if (t == 0) {
        float m = rs[0] / NN;
        float var = rq[0] / NN - m * m;
        mu[f] = m;
        rinv[f] = rsqrtf(var + 1e-5f);
      }
    }
  }
  gsync(bar, 7);

  // ---- P8: final linear (fused BN2+ReLU) + mask + updated_pos (640 items x 4) ----
  {
    for (int it = bid; it < NN / 4; it += GRID) {
      int w = t >> 6, lane = t & 63;
      int n = it * 4 + w;
      float r0 = 0.f, r1 = 0.f;
      for (int c = lane; c < HC; c += 64) {
        float v = fmaxf((ldh(o, n * HC + c) - mu[c]) * rinv[c] * g2[c] + be2[c], 0.f);
        r0 += v * Wf[c * 2];
        r1 += v * Wf[c * 2 + 1];
      }
      for (int oo = 32; oo > 0; oo >>= 1) {
        r0 += __shfl_down(r0, oo);
        r1 += __shfl_down(r1, oo);
      }
      if (lane == 0) {
        float mk = mask[n];
        float o0 = (r0 + bfv[0]) * mk;
        float o1 = (r1 + bfv[1]) * mk;
        out[n * 2]     = o0;
        out[n * 2 + 1] = o1;
        out[2 * NN + n * 2]     = pos[n * 2]     + o0;
        out[2 * NN + n * 2 + 1] = pos[n * 2 + 1] + o1;
      }
    }
  }
}

extern "C" void kernel_launch(void* const* d_in, const int* in_sizes, int n_in,
                              void* d_out, int out_size, void* d_ws, size_t ws_size,
                              hipStream_t stream) {
  (void)in_sizes; (void)n_in; (void)out_size; (void)ws_size;
  const float* x    = (const float*)d_in[0];
  const int*   ei   = (const int*)d_in[1];
  const float* pos  = (const float*)d_in[2];
  const float* mask = (const float*)d_in[3];
  // d_in[4] = batch (int32), unused
  const float* W1   = (const float*)d_in[5];
  const float* as1  = (const float*)d_in[6];
  const float* ad1  = (const float*)d_in[7];
  const float* b1   = (const float*)d_in[8];
  const float* g1   = (const float*)d_in[9];
  const float* be1  = (const float*)d_in[10];
  const float* W2   = (const float*)d_in[11];
  const float* as2  = (const float*)d_in[12];
  const float* ad2  = (const float*)d_in[13];
  const float* b2   = (const float*)d_in[14];
  const float* g2   = (const float*)d_in[15];
  const float* be2  = (const float*)d_in[16];
  const float* Wf   = (const float*)d_in[17];
  const float* bfv  = (const float*)d_in[18];

  const int* srcp = ei;
  const int* dstp = ei + EE;

  // ws layout — ~3.93 MB (proven ws_size >= 4,077,568 B):
  //  bar int[16] | agg f32[5120] asb[10240] adb[10240] mu[256] rinv[256]
  //  cntd int[2560] | esrcB u16[2560*240] | o __half[655360] | h __half[655360]
  int* bar    = (int*)d_ws;
  float* agg  = (float*)(bar + 16);
  float* asb  = agg + 5120;
  float* adb  = asb + 10240;
  float* mu   = adb + 10240;
  float* rinv = mu + 256;
  int* cntd   = (int*)(rinv + 256);
  u16* esrcB  = (u16*)(cntd + 2560);
  __half* o   = (__half*)(esrcB + 2560 * CAP);
  __half* h   = o + 655360;

  hipMemsetAsync(bar, 0, 16 * sizeof(int), stream);
  k_mega<<<GRID, 256, 0, stream>>>(x, srcp, dstp, pos, mask,
                                   W1, as1, ad1, b1, g1, be1,
                                   W2, as2, ad2, b2, g2, be2, Wf, bfv,
                                   (float*)d_out,
                                   agg, asb, adb, mu, rinv, cntd, esrcB, o, h, bar);
}

// Round 17
// 149.207 us; speedup vs baseline: 6.9271x; 6.9271x over previous
//
#include <hip/hip_runtime.h>
#include <hip/hip_fp16.h>
#include <math.h>

typedef unsigned short u16;

#define NN 2560
#define EE 327680
#define HC 256         // H*C
#define FIN 62
#define CAP 240        // per-node global bucket capacity (max degree+1 ~ 181)
#define NCH 32         // edge chunks
#define CHSZ (EE / NCH)  // 10240
#define PCAP 32        // per-(node,chunk) LDS bucket capacity

__device__ __forceinline__ float lrelu(float x) { return x >= 0.f ? x : 0.2f * x; }
__device__ __forceinline__ float ldh(const __half* p, int i) { return __half2float(p[i]); }

// ---------- init: self-loop pre-seeded in dst buckets; agg zeroed ----------
__global__ void k_init(int* __restrict__ cntd, u16* __restrict__ esrcB,
                       float* __restrict__ agg) {
  int n = blockIdx.x * 256 + threadIdx.x;
  if (n >= NN) return;
  cntd[n] = 1;
  esrcB[n * CAP] = (u16)n;
  agg[2 * n] = 0.f;
  agg[2 * n + 1] = 0.f;
}

// ---------- binning + fused edge-feature aggregation ----------
__global__ void k_bin(const int* __restrict__ src, const int* __restrict__ dst,
                      const float* __restrict__ pos, int* __restrict__ cntd,
                      u16* __restrict__ esrcB, float* __restrict__ agg) {
  __shared__ u16 bufD[64][PCAP];
  __shared__ int cD[64], baseD[64];
  __shared__ float aggD[64], aggA[64];
  int t = threadIdx.x;
  int c = blockIdx.x;   // edge chunk
  int r = blockIdx.y;   // 64-node range
  if (t < 64) { cD[t] = 0; aggD[t] = 0.f; aggA[t] = 0.f; }
  __syncthreads();
  int e0 = c * CHSZ;
  const int4* s4p = (const int4*)(src + e0);
  const int4* d4p = (const int4*)(dst + e0);
  for (int i = t; i < CHSZ / 4; i += 256) {
    int4 s4 = s4p[i];
    int4 d4 = d4p[i];
    int ss[4] = {s4.x, s4.y, s4.z, s4.w};
    int dd[4] = {d4.x, d4.y, d4.z, d4.w};
#pragma unroll
    for (int k = 0; k < 4; ++k) {
      int s = ss[k], d = dd[k];
      if ((d >> 6) == r) {
        int p = atomicAdd(&cD[d & 63], 1);
        if (p < PCAP) {
          bufD[d & 63][p] = (u16)s;
        } else {  // guaranteed-correct spill (disjoint slots vs batch reserve)
          int idx = atomicAdd(&cntd[d], 1);
          esrcB[d * CAP + idx] = (u16)s;
        }
      }
      if ((s >> 6) == r) {
        float2 psv = ((const float2*)pos)[s];
        float2 pdv = ((const float2*)pos)[d];
        float dx = pdv.x - psv.x, dy = pdv.y - psv.y;
        atomicAdd(&aggD[s & 63], sqrtf(dx * dx + dy * dy));
        atomicAdd(&aggA[s & 63], atan2f(dy, dx));
      }
    }
  }
  __syncthreads();
  if (t < 64) baseD[t] = atomicAdd(&cntd[r * 64 + t], min(cD[t], PCAP));
  __syncthreads();
  for (int idx = t; idx < 64 * PCAP; idx += 256) {
    int n = idx >> 5;   // PCAP == 32
    int i = idx & 31;
    if (i < min(cD[n], PCAP)) esrcB[(r * 64 + n) * CAP + baseD[n] + i] = bufD[n][i];
  }
  if (t < 64) {
    atomicAdd(&agg[2 * (r * 64 + t)], aggD[t]);
    atomicAdd(&agg[2 * (r * 64 + t) + 1], aggA[t]);
  }
}

// ---------- layer-1 GEMM: 4 nodes/block, fused concat + alpha epilogue ----------
__global__ void k_gemm1(const float* __restrict__ x, const float* __restrict__ agg,
                        const float* __restrict__ W, const float* __restrict__ a_src,
                        const float* __restrict__ a_dst,
                        __half* __restrict__ Hout, float* __restrict__ asb,
                        float* __restrict__ adb) {
  __shared__ float xrow[4][64];
  int n0 = blockIdx.x * 4, t = threadIdx.x;
  int m0 = t >> 6, i0 = t & 63;
  xrow[m0][i0] = (i0 < FIN) ? x[(n0 + m0) * FIN + i0] : agg[(n0 + m0) * 2 + (i0 - FIN)];
  __syncthreads();
  float a0 = 0.f, a1 = 0.f, a2 = 0.f, a3 = 0.f;
#pragma unroll 8
  for (int k = 0; k < 64; ++k) {
    float w = W[k * HC + t];
    a0 += xrow[0][k] * w; a1 += xrow[1][k] * w;
    a2 += xrow[2][k] * w; a3 += xrow[3][k] * w;
  }
  Hout[(n0 + 0) * HC + t] = __float2half(a0);
  Hout[(n0 + 1) * HC + t] = __float2half(a1);
  Hout[(n0 + 2) * HC + t] = __float2half(a2);
  Hout[(n0 + 3) * HC + t] = __float2half(a3);
  float accs[4] = {a0, a1, a2, a3};
  int h = t >> 6, lane = t & 63;
  float vs = a_src[t], vdd = a_dst[t];
#pragma unroll
  for (int m = 0; m < 4; ++m) {
    float p1 = accs[m] * vs;
    float p2 = accs[m] * vdd;
    for (int o = 32; o > 0; o >>= 1) {
      p1 += __shfl_down(p1, o);
      p2 += __shfl_down(p2, o);
    }
    if (lane == 0) {
      asb[(n0 + m) * 4 + h] = p1;
      adb[(n0 + m) * 4 + h] = p2;
    }
  }
}

// ---------- layer-2 GEMM: 8 nodes/block, fused BN1+ReLU + alpha epilogue ----------
__global__ void k_gemm2(const __half* __restrict__ X, const float* __restrict__ mu,
                        const float* __restrict__ rinv, const float* __restrict__ g,
                        const float* __restrict__ be, const float* __restrict__ W,
                        const float* __restrict__ a_src, const float* __restrict__ a_dst,
                        __half* __restrict__ Hout, float* __restrict__ asb,
                        float* __restrict__ adb) {
  __shared__ float xrow[8][256];
  int n0 = blockIdx.x * 8, t = threadIdx.x;
  float bmu = mu[t], brv = rinv[t], bg = g[t], bb = be[t];
#pragma unroll
  for (int m = 0; m < 8; ++m)
    xrow[m][t] = fmaxf((ldh(X, (n0 + m) * HC + t) - bmu) * brv * bg + bb, 0.f);
  __syncthreads();
  float acc[8] = {0.f, 0.f, 0.f, 0.f, 0.f, 0.f, 0.f, 0.f};
#pragma unroll 2
  for (int k = 0; k < 256; ++k) {
    float w = W[k * HC + t];
#pragma unroll
    for (int m = 0; m < 8; ++m) acc[m] += xrow[m][k] * w;
  }
#pragma unroll
  for (int m = 0; m < 8; ++m)
    Hout[(n0 + m) * HC + t] = __float2half(acc[m]);
  int h = t >> 6, lane = t & 63;
  float vs = a_src[t], vdd = a_dst[t];
#pragma unroll
  for (int m = 0; m < 8; ++m) {
    float p1 = acc[m] * vs;
    float p2 = acc[m] * vdd;
    for (int o = 32; o > 0; o >>= 1) {
      p1 += __shfl_down(p1, o);
      p2 += __shfl_down(p2, o);
    }
    if (lane == 0) {
      asb[(n0 + m) * 4 + h] = p1;
      adb[(n0 + m) * 4 + h] = p2;
    }
  }
}

// ---------- GAT aggregate per dst node: half2 gather (validated in R16) ----------
__global__ void k_agg(const int* __restrict__ cntd, const u16* __restrict__ esrcB,
                      const float* __restrict__ asb, const float* __restrict__ adb,
                      const __half* __restrict__ Hin, const float* __restrict__ bias,
                      __half* __restrict__ Out) {
  __shared__ float eE[4][256];
  __shared__ int sS[256];
  __shared__ float2 accbuf[256];
  __shared__ float wred[4][4];
  int n = blockIdx.x, t = threadIdx.x;
  int cnt = min(cntd[n], CAP);

  float ad0 = adb[n * 4 + 0], ad1 = adb[n * 4 + 1];
  float ad2 = adb[n * 4 + 2], ad3 = adb[n * 4 + 3];

  float e0 = 0.f, e1 = 0.f, e2 = 0.f, e3 = 0.f;
  int s = 0;
  if (t < cnt) {
    s = (int)esrcB[n * CAP + t];
    e0 = expf(lrelu(asb[s * 4 + 0] + ad0));
    e1 = expf(lrelu(asb[s * 4 + 1] + ad1));
    e2 = expf(lrelu(asb[s * 4 + 2] + ad2));
    e3 = expf(lrelu(asb[s * 4 + 3] + ad3));
  }
  eE[0][t] = e0; eE[1][t] = e1; eE[2][t] = e2; eE[3][t] = e3;
  sS[t] = s;
  float d0 = e0, d1 = e1, d2 = e2, d3 = e3;
  for (int o = 32; o > 0; o >>= 1) {
    d0 += __shfl_down(d0, o);
    d1 += __shfl_down(d1, o);
    d2 += __shfl_down(d2, o);
    d3 += __shfl_down(d3, o);
  }
  if ((t & 63) == 0) {
    wred[t >> 6][0] = d0; wred[t >> 6][1] = d1;
    wred[t >> 6][2] = d2; wred[t >> 6][3] = d3;
  }
  __syncthreads();

  // 2 row-groups x 128 half2 columns: 4B/lane gathers, 2 rows in flight
  int grp = t >> 7, c2 = t & 127, hh = c2 >> 5;
  const __half2* H2 = (const __half2*)Hin;
  float accx = 0.f, accy = 0.f;
  for (int j = grp; j < cnt; j += 2) {
    float w = eE[hh][j];
    float2 f = __half22float2(H2[sS[j] * 128 + c2]);
    accx += w * f.x; accy += w * f.y;
  }
  accbuf[t] = make_float2(accx, accy);
  __syncthreads();
  if (t < 128) {
    float2 a0 = accbuf[t], a1 = accbuf[t + 128];
    int hh2 = t >> 5;
    float den = wred[0][hh2] + wred[1][hh2] + wred[2][hh2] + wred[3][hh2] + 1e-16f;
    __half2 r;
    r.x = __float2half((a0.x + a1.x) / den + bias[2 * t]);
    r.y = __float2half((a0.y + a1.y) / den + bias[2 * t + 1]);
    ((__half2*)Out)[n * 128 + t] = r;
  }
}

// ---------- BN stats ----------
__global__ void k_bnstats(const __half* __restrict__ X, float* __restrict__ mu,
                          float* __restrict__ rinv) {
  __shared__ float rs[256];
  __shared__ float rq[256];
  int f = blockIdx.x, t = threadIdx.x;
  float s = 0.f, sq = 0.f;
  for (int n = t; n < NN; n += 256) {
    float v = ldh(X, n * HC + f);
    s += v;
    sq += v * v;
  }
  rs[t] = s; rq[t] = sq;
  __syncthreads();
  for (int o = 128; o > 0; o >>= 1) {
    if (t < o) { rs[t] += rs[t + o]; rq[t] += rq[t + o]; }
    __syncthreads();
  }
  if (t == 0) {
    float m = rs[0] / NN;
    float var = rq[0] / NN - m * m;
    mu[f] = m;
    rinv[f] = rsqrtf(var + 1e-5f);
  }
}

// ---------- final linear (fused BN2+ReLU) + mask + updated_pos ----------
__global__ void k_final(const __half* __restrict__ X, const float* __restrict__ mu,
                        const float* __restrict__ rinv, const float* __restrict__ g,
                        const float* __restrict__ be, const float* __restrict__ Wf,
                        const float* __restrict__ bfv, const float* __restrict__ mask,
                        const float* __restrict__ pos, float* __restrict__ out) {
  int n = blockIdx.x, l = threadIdx.x;  // 64 threads
  float r0 = 0.f, r1 = 0.f;
  for (int c = l; c < HC; c += 64) {
    float v = fmaxf((ldh(X, n * HC + c) - mu[c]) * rinv[c] * g[c] + be[c], 0.f);
    r0 += v * Wf[c * 2];
    r1 += v * Wf[c * 2 + 1];
  }
  for (int o = 32; o > 0; o >>= 1) {
    r0 += __shfl_down(r0, o);
    r1 += __shfl_down(r1, o);
  }
  if (l == 0) {
    float mk = mask[n];
    float o0 = (r0 + bfv[0]) * mk;
    float o1 = (r1 + bfv[1]) * mk;
    out[n * 2]     = o0;
    out[n * 2 + 1] = o1;
    out[2 * NN + n * 2]     = pos[n * 2]     + o0;
    out[2 * NN + n * 2 + 1] = pos[n * 2 + 1] + o1;
  }
}

extern "C" void kernel_launch(void* const* d_in, const int* in_sizes, int n_in,
                              void* d_out, int out_size, void* d_ws, size_t ws_size,
                              hipStream_t stream) {
  (void)in_sizes; (void)n_in; (void)out_size; (void)ws_size;
  const float* x    = (const float*)d_in[0];
  const int*   ei   = (const int*)d_in[1];
  const float* pos  = (const float*)d_in[2];
  const float* mask = (const float*)d_in[3];
  // d_in[4] = batch (int32), unused
  const float* W1   = (const float*)d_in[5];
  const float* as1  = (const float*)d_in[6];
  const float* ad1  = (const float*)d_in[7];
  const float* b1   = (const float*)d_in[8];
  const float* g1   = (const float*)d_in[9];
  const float* be1  = (const float*)d_in[10];
  const float* W2   = (const float*)d_in[11];
  const float* as2  = (const float*)d_in[12];
  const float* ad2  = (const float*)d_in[13];
  const float* b2   = (const float*)d_in[14];
  const float* g2   = (const float*)d_in[15];
  const float* be2  = (const float*)d_in[16];
  const float* Wf   = (const float*)d_in[17];
  const float* bfv  = (const float*)d_in[18];

  const int* srcp = ei;
  const int* dstp = ei + EE;

  // ws layout — ~3.93 MB (proven ws_size >= 4,077,568 B):
  //  agg f32[5120] asb[10240] adb[10240] mu[256] rinv[256] cntd int[2560]
  //  esrcB u16[2560*240] | o __half[655360] | h __half[655360]
  float* ws   = (float*)d_ws;
  float* agg  = ws;
  float* asb  = agg + 5120;
  float* adb  = asb + 10240;
  float* mu   = adb + 10240;
  float* rinv = mu + 256;
  int* cntd   = (int*)(rinv + 256);
  u16* esrcB  = (u16*)(cntd + 2560);
  __half* o   = (__half*)(esrcB + 2560 * CAP);
  __half* h   = o + 655360;

  k_init<<<(NN + 255) / 256, 256, 0, stream>>>(cntd, esrcB, agg);
  dim3 grid_bin(NCH, NN / 64);
  k_bin<<<grid_bin, 256, 0, stream>>>(srcp, dstp, pos, cntd, esrcB, agg);

  // ---- layer 1 ----
  k_gemm1<<<NN / 4, 256, 0, stream>>>(x, agg, W1, as1, ad1, h, asb, adb);
  k_agg<<<NN, 256, 0, stream>>>(cntd, esrcB, asb, adb, h, b1, o);
  k_bnstats<<<HC, 256, 0, stream>>>(o, mu, rinv);

  // ---- layer 2 (BN1 fused into gemm2 load) ----
  k_gemm2<<<NN / 8, 256, 0, stream>>>(o, mu, rinv, g1, be1, W2, as2, ad2, h, asb, adb);
  k_agg<<<NN, 256, 0, stream>>>(cntd, esrcB, asb, adb, h, b2, o);
  k_bnstats<<<HC, 256, 0, stream>>>(o, mu, rinv);

  // ---- final (BN2 fused) ----
  k_final<<<NN, 64, 0, stream>>>(o, mu, rinv, g2, be2, Wf, bfv, mask, pos, (float*)d_out);
}

// Round 18
// 136.440 us; speedup vs baseline: 7.5753x; 1.0936x over previous
//
#include <hip/hip_runtime.h>
#include <hip/hip_fp16.h>
#include <math.h>

typedef unsigned short u16;

#define NN 2560
#define EE 327680
#define HC 256         // H*C
#define FIN 62
#define CAP 240        // per-node global bucket capacity (max degree+1 ~ 181)
#define NCH 32         // edge chunks
#define CHSZ (EE / NCH)  // 10240
#define PCAP 32        // per-(node,chunk) LDS bucket capacity

__device__ __forceinline__ float lrelu(float x) { return x >= 0.f ? x : 0.2f * x; }
__device__ __forceinline__ float ldh(const __half* p, int i) { return __half2float(p[i]); }

// ---------- init: self-loop pre-seeded in dst buckets; agg zeroed ----------
__global__ void k_init(int* __restrict__ cntd, u16* __restrict__ esrcB,
                       float* __restrict__ agg) {
  int n = blockIdx.x * 256 + threadIdx.x;
  if (n >= NN) return;
  cntd[n] = 1;
  esrcB[n * CAP] = (u16)n;
  agg[2 * n] = 0.f;
  agg[2 * n + 1] = 0.f;
}

// ---------- binning + fused edge-feature aggregation ----------
__global__ void k_bin(const int* __restrict__ src, const int* __restrict__ dst,
                      const float* __restrict__ pos, int* __restrict__ cntd,
                      u16* __restrict__ esrcB, float* __restrict__ agg) {
  __shared__ u16 bufD[64][PCAP];
  __shared__ int cD[64], baseD[64];
  __shared__ float aggD[64], aggA[64];
  int t = threadIdx.x;
  int c = blockIdx.x;   // edge chunk
  int r = blockIdx.y;   // 64-node range
  if (t < 64) { cD[t] = 0; aggD[t] = 0.f; aggA[t] = 0.f; }
  __syncthreads();
  int e0 = c * CHSZ;
  const int4* s4p = (const int4*)(src + e0);
  const int4* d4p = (const int4*)(dst + e0);
  for (int i = t; i < CHSZ / 4; i += 256) {
    int4 s4 = s4p[i];
    int4 d4 = d4p[i];
    int ss[4] = {s4.x, s4.y, s4.z, s4.w};
    int dd[4] = {d4.x, d4.y, d4.z, d4.w};
#pragma unroll
    for (int k = 0; k < 4; ++k) {
      int s = ss[k], d = dd[k];
      if ((d >> 6) == r) {
        int p = atomicAdd(&cD[d & 63], 1);
        if (p < PCAP) {
          bufD[d & 63][p] = (u16)s;
        } else {  // guaranteed-correct spill (disjoint slots vs batch reserve)
          int idx = atomicAdd(&cntd[d], 1);
          esrcB[d * CAP + idx] = (u16)s;
        }
      }
      if ((s >> 6) == r) {
        float2 psv = ((const float2*)pos)[s];
        float2 pdv = ((const float2*)pos)[d];
        float dx = pdv.x - psv.x, dy = pdv.y - psv.y;
        atomicAdd(&aggD[s & 63], sqrtf(dx * dx + dy * dy));
        atomicAdd(&aggA[s & 63], atan2f(dy, dx));
      }
    }
  }
  __syncthreads();
  if (t < 64) baseD[t] = atomicAdd(&cntd[r * 64 + t], min(cD[t], PCAP));
  __syncthreads();
  for (int idx = t; idx < 64 * PCAP; idx += 256) {
    int n = idx >> 5;   // PCAP == 32
    int i = idx & 31;
    if (i < min(cD[n], PCAP)) esrcB[(r * 64 + n) * CAP + baseD[n] + i] = bufD[n][i];
  }
  if (t < 64) {
    atomicAdd(&agg[2 * (r * 64 + t)], aggD[t]);
    atomicAdd(&agg[2 * (r * 64 + t) + 1], aggA[t]);
  }
}

// ---------- layer-1 GEMM: 4 nodes/block, fused concat + alpha epilogue ----------
__global__ void k_gemm1(const float* __restrict__ x, const float* __restrict__ agg,
                        const float* __restrict__ W, const float* __restrict__ a_src,
                        const float* __restrict__ a_dst,
                        __half* __restrict__ Hout, float* __restrict__ asb,
                        float* __restrict__ adb) {
  __shared__ float xrow[4][64];
  int n0 = blockIdx.x * 4, t = threadIdx.x;
  int m0 = t >> 6, i0 = t & 63;
  xrow[m0][i0] = (i0 < FIN) ? x[(n0 + m0) * FIN + i0] : agg[(n0 + m0) * 2 + (i0 - FIN)];
  __syncthreads();
  float a0 = 0.f, a1 = 0.f, a2 = 0.f, a3 = 0.f;
#pragma unroll 8
  for (int k = 0; k < 64; ++k) {
    float w = W[k * HC + t];
    a0 += xrow[0][k] * w; a1 += xrow[1][k] * w;
    a2 += xrow[2][k] * w; a3 += xrow[3][k] * w;
  }
  Hout[(n0 + 0) * HC + t] = __float2half(a0);
  Hout[(n0 + 1) * HC + t] = __float2half(a1);
  Hout[(n0 + 2) * HC + t] = __float2half(a2);
  Hout[(n0 + 3) * HC + t] = __float2half(a3);
  float accs[4] = {a0, a1, a2, a3};
  int h = t >> 6, lane = t & 63;
  float vs = a_src[t], vdd = a_dst[t];
#pragma unroll
  for (int m = 0; m < 4; ++m) {
    float p1 = accs[m] * vs;
    float p2 = accs[m] * vdd;
    for (int o = 32; o > 0; o >>= 1) {
      p1 += __shfl_down(p1, o);
      p2 += __shfl_down(p2, o);
    }
    if (lane == 0) {
      asb[(n0 + m) * 4 + h] = p1;
      adb[(n0 + m) * 4 + h] = p2;
    }
  }
}

// ---------- layer-2 GEMM: 4 nodes/block (R15 proven config), fused BN1+ReLU ----------
__global__ void k_gemm2(const __half* __restrict__ X, const float* __restrict__ mu,
                        const float* __restrict__ rinv, const float* __restrict__ g,
                        const float* __restrict__ be, const float* __restrict__ W,
                        const float* __restrict__ a_src, const float* __restrict__ a_dst,
                        __half* __restrict__ Hout, float* __restrict__ asb,
                        float* __restrict__ adb) {
  __shared__ float xrow[4][256];
  int n0 = blockIdx.x * 4, t = threadIdx.x;
  float bmu = mu[t], brv = rinv[t], bg = g[t], bb = be[t];
#pragma unroll
  for (int m = 0; m < 4; ++m)
    xrow[m][t] = fmaxf((ldh(X, (n0 + m) * HC + t) - bmu) * brv * bg + bb, 0.f);
  __syncthreads();
  float a0 = 0.f, a1 = 0.f, a2 = 0.f, a3 = 0.f;
#pragma unroll 4
  for (int k = 0; k < 256; ++k) {
    float w = W[k * HC + t];
    a0 += xrow[0][k] * w; a1 += xrow[1][k] * w;
    a2 += xrow[2][k] * w; a3 += xrow[3][k] * w;
  }
  Hout[(n0 + 0) * HC + t] = __float2half(a0);
  Hout[(n0 + 1) * HC + t] = __float2half(a1);
  Hout[(n0 + 2) * HC + t] = __float2half(a2);
  Hout[(n0 + 3) * HC + t] = __float2half(a3);
  float accs[4] = {a0, a1, a2, a3};
  int h = t >> 6, lane = t & 63;
  float vs = a_src[t], vdd = a_dst[t];
#pragma unroll
  for (int m = 0; m < 4; ++m) {
    float p1 = accs[m] * vs;
    float p2 = accs[m] * vdd;
    for (int o = 32; o > 0; o >>= 1) {
      p1 += __shfl_down(p1, o);
      p2 += __shfl_down(p2, o);
    }
    if (lane == 0) {
      asb[(n0 + m) * 4 + h] = p1;
      adb[(n0 + m) * 4 + h] = p2;
    }
  }
}

// ---------- GAT aggregate per dst node: half2 gather (validated R16/R17) ----------
__global__ void k_agg(const int* __restrict__ cntd, const u16* __restrict__ esrcB,
                      const float* __restrict__ asb, const float* __restrict__ adb,
                      const __half* __restrict__ Hin, const float* __restrict__ bias,
                      __half* __restrict__ Out) {
  __shared__ float eE[4][256];
  __shared__ int sS[256];
  __shared__ float2 accbuf[256];
  __shared__ float wred[4][4];
  int n = blockIdx.x, t = threadIdx.x;
  int cnt = min(cntd[n], CAP);

  float ad0 = adb[n * 4 + 0], ad1 = adb[n * 4 + 1];
  float ad2 = adb[n * 4 + 2], ad3 = adb[n * 4 + 3];

  float e0 = 0.f, e1 = 0.f, e2 = 0.f, e3 = 0.f;
  int s = 0;
  if (t < cnt) {
    s = (int)esrcB[n * CAP + t];
    e0 = expf(lrelu(asb[s * 4 + 0] + ad0));
    e1 = expf(lrelu(asb[s * 4 + 1] + ad1));
    e2 = expf(lrelu(asb[s * 4 + 2] + ad2));
    e3 = expf(lrelu(asb[s * 4 + 3] + ad3));
  }
  eE[0][t] = e0; eE[1][t] = e1; eE[2][t] = e2; eE[3][t] = e3;
  sS[t] = s;
  float d0 = e0, d1 = e1, d2 = e2, d3 = e3;
  for (int o = 32; o > 0; o >>= 1) {
    d0 += __shfl_down(d0, o);
    d1 += __shfl_down(d1, o);
    d2 += __shfl_down(d2, o);
    d3 += __shfl_down(d3, o);
  }
  if ((t & 63) == 0) {
    wred[t >> 6][0] = d0; wred[t >> 6][1] = d1;
    wred[t >> 6][2] = d2; wred[t >> 6][3] = d3;
  }
  __syncthreads();

  // 2 row-groups x 128 half2 columns: 4B/lane gathers, 2 rows in flight
  int grp = t >> 7, c2 = t & 127, hh = c2 >> 5;
  const __half2* H2 = (const __half2*)Hin;
  float accx = 0.f, accy = 0.f;
  for (int j = grp; j < cnt; j += 2) {
    float w = eE[hh][j];
    float2 f = __half22float2(H2[sS[j] * 128 + c2]);
    accx += w * f.x; accy += w * f.y;
  }
  accbuf[t] = make_float2(accx, accy);
  __syncthreads();
  if (t < 128) {
    float2 a0 = accbuf[t], a1 = accbuf[t + 128];
    int hh2 = t >> 5;
    float den = wred[0][hh2] + wred[1][hh2] + wred[2][hh2] + wred[3][hh2] + 1e-16f;
    __half2 r;
    r.x = __float2half((a0.x + a1.x) / den + bias[2 * t]);
    r.y = __float2half((a0.y + a1.y) / den + bias[2 * t + 1]);
    ((__half2*)Out)[n * 128 + t] = r;
  }
}

// ---------- BN stats ----------
__global__ void k_bnstats(const __half* __restrict__ X, float* __restrict__ mu,
                          float* __restrict__ rinv) {
  __shared__ float rs[256];
  __shared__ float rq[256];
  int f = blockIdx.x, t = threadIdx.x;
  float s = 0.f, sq = 0.f;
  for (int n = t; n < NN; n += 256) {
    float v = ldh(X, n * HC + f);
    s += v;
    sq += v * v;
  }
  rs[t] = s; rq[t] = sq;
  __syncthreads();
  for (int o = 128; o > 0; o >>= 1) {
    if (t < o) { rs[t] += rs[t + o]; rq[t] += rq[t + o]; }
    __syncthreads();
  }
  if (t == 0) {
    float m = rs[0] / NN;
    float var = rq[0] / NN - m * m;
    mu[f] = m;
    rinv[f] = rsqrtf(var + 1e-5f);
  }
}

// ---------- final linear (fused BN2+ReLU) + mask + updated_pos ----------
__global__ void k_final(const __half* __restrict__ X, const float* __restrict__ mu,
                        const float* __restrict__ rinv, const float* __restrict__ g,
                        const float* __restrict__ be, const float* __restrict__ Wf,
                        const float* __restrict__ bfv, const float* __restrict__ mask,
                        const float* __restrict__ pos, float* __restrict__ out) {
  int n = blockIdx.x, l = threadIdx.x;  // 64 threads
  float r0 = 0.f, r1 = 0.f;
  for (int c = l; c < HC; c += 64) {
    float v = fmaxf((ldh(X, n * HC + c) - mu[c]) * rinv[c] * g[c] + be[c], 0.f);
    r0 += v * Wf[c * 2];
    r1 += v * Wf[c * 2 + 1];
  }
  for (int o = 32; o > 0; o >>= 1) {
    r0 += __shfl_down(r0, o);
    r1 += __shfl_down(r1, o);
  }
  if (l == 0) {
    float mk = mask[n];
    float o0 = (r0 + bfv[0]) * mk;
    float o1 = (r1 + bfv[1]) * mk;
    out[n * 2]     = o0;
    out[n * 2 + 1] = o1;
    out[2 * NN + n * 2]     = pos[n * 2]     + o0;
    out[2 * NN + n * 2 + 1] = pos[n * 2 + 1] + o1;
  }
}

extern "C" void kernel_launch(void* const* d_in, const int* in_sizes, int n_in,
                              void* d_out, int out_size, void* d_ws, size_t ws_size,
                              hipStream_t stream) {
  (void)in_sizes; (void)n_in; (void)out_size; (void)ws_size;
  const float* x    = (const float*)d_in[0];
  const int*   ei   = (const int*)d_in[1];
  const float* pos  = (const float*)d_in[2];
  const float* mask = (const float*)d_in[3];
  // d_in[4] = batch (int32), unused
  const float* W1   = (const float*)d_in[5];
  const float* as1  = (const float*)d_in[6];
  const float* ad1  = (const float*)d_in[7];
  const float* b1   = (const float*)d_in[8];
  const float* g1   = (const float*)d_in[9];
  const float* be1  = (const float*)d_in[10];
  const float* W2   = (const float*)d_in[11];
  const float* as2  = (const float*)d_in[12];
  const float* ad2  = (const float*)d_in[13];
  const float* b2   = (const float*)d_in[14];
  const float* g2   = (const float*)d_in[15];
  const float* be2  = (const float*)d_in[16];
  const float* Wf   = (const float*)d_in[17];
  const float* bfv  = (const float*)d_in[18];

  const int* srcp = ei;
  const int* dstp = ei + EE;

  // ws layout — ~3.93 MB (proven ws_size >= 4,077,568 B):
  //  agg f32[5120] asb[10240] adb[10240] mu[256] rinv[256] cntd int[2560]
  //  esrcB u16[2560*240] | o __half[655360] | h __half[655360]
  float* ws   = (float*)d_ws;
  float* agg  = ws;
  float* asb  = agg + 5120;
  float* adb  = asb + 10240;
  float* mu   = adb + 10240;
  float* rinv = mu + 256;
  int* cntd   = (int*)(rinv + 256);
  u16* esrcB  = (u16*)(cntd + 2560);
  __half* o   = (__half*)(esrcB + 2560 * CAP);
  __half* h   = o + 655360;

  k_init<<<(NN + 255) / 256, 256, 0, stream>>>(cntd, esrcB, agg);
  dim3 grid_bin(NCH, NN / 64);
  k_bin<<<grid_bin, 256, 0, stream>>>(srcp, dstp, pos, cntd, esrcB, agg);

  // ---- layer 1 ----
  k_gemm1<<<NN / 4, 256, 0, stream>>>(x, agg, W1, as1, ad1, h, asb, adb);
  k_agg<<<NN, 256, 0, stream>>>(cntd, esrcB, asb, adb, h, b1, o);
  k_bnstats<<<HC, 256, 0, stream>>>(o, mu, rinv);

  // ---- layer 2 (BN1 fused into gemm2 load) ----
  k_gemm2<<<NN / 4, 256, 0, stream>>>(o, mu, rinv, g1, be1, W2, as2, ad2, h, asb, adb);
  k_agg<<<NN, 256, 0, stream>>>(cntd, esrcB, asb, adb, h, b2, o);
  k_bnstats<<<HC, 256, 0, stream>>>(o, mu, rinv);

  // ---- final (BN2 fused) ----
  k_final<<<NN, 64, 0, stream>>>(o, mu, rinv, g2, be2, Wf, bfv, mask, pos, (float*)d_out);
}

// Round 19
// 121.690 us; speedup vs baseline: 8.4935x; 1.1212x over previous
//
#include <hip/hip_runtime.h>
#include <hip/hip_fp16.h>
#include <math.h>

typedef unsigned short u16;

#define NN 2560
#define EE 327680
#define HC 256         // H*C
#define FIN 62
#define CAP 240        // per-node global bucket capacity (max degree+1 ~ 181)
#define NCH 32         // edge chunks
#define CHSZ (EE / NCH)  // 10240
#define PCAP 32        // per-(node,chunk) LDS bucket capacity

__device__ __forceinline__ float lrelu(float x) { return x >= 0.f ? x : 0.2f * x; }
__device__ __forceinline__ float ldh(const __half* p, int i) { return __half2float(p[i]); }

// ---------- init: self-loop pre-seeded in dst buckets; agg zeroed ----------
__global__ void k_init(int* __restrict__ cntd, u16* __restrict__ esrcB,
                       float* __restrict__ agg) {
  int n = blockIdx.x * 256 + threadIdx.x;
  if (n >= NN) return;
  cntd[n] = 1;
  esrcB[n * CAP] = (u16)n;
  agg[2 * n] = 0.f;
  agg[2 * n + 1] = 0.f;
}

// ---------- binning + fused edge-feature aggregation ----------
__global__ void k_bin(const int* __restrict__ src, const int* __restrict__ dst,
                      const float* __restrict__ pos, int* __restrict__ cntd,
                      u16* __restrict__ esrcB, float* __restrict__ agg) {
  __shared__ u16 bufD[64][PCAP];
  __shared__ int cD[64], baseD[64];
  __shared__ float aggD[64], aggA[64];
  int t = threadIdx.x;
  int c = blockIdx.x;   // edge chunk
  int r = blockIdx.y;   // 64-node range
  if (t < 64) { cD[t] = 0; aggD[t] = 0.f; aggA[t] = 0.f; }
  __syncthreads();
  int e0 = c * CHSZ;
  const int4* s4p = (const int4*)(src + e0);
  const int4* d4p = (const int4*)(dst + e0);
  for (int i = t; i < CHSZ / 4; i += 256) {
    int4 s4 = s4p[i];
    int4 d4 = d4p[i];
    int ss[4] = {s4.x, s4.y, s4.z, s4.w};
    int dd[4] = {d4.x, d4.y, d4.z, d4.w};
#pragma unroll
    for (int k = 0; k < 4; ++k) {
      int s = ss[k], d = dd[k];
      if ((d >> 6) == r) {
        int p = atomicAdd(&cD[d & 63], 1);
        if (p < PCAP) {
          bufD[d & 63][p] = (u16)s;
        } else {  // guaranteed-correct spill (disjoint slots vs batch reserve)
          int idx = atomicAdd(&cntd[d], 1);
          esrcB[d * CAP + idx] = (u16)s;
        }
      }
      if ((s >> 6) == r) {
        float2 psv = ((const float2*)pos)[s];
        float2 pdv = ((const float2*)pos)[d];
        float dx = pdv.x - psv.x, dy = pdv.y - psv.y;
        atomicAdd(&aggD[s & 63], sqrtf(dx * dx + dy * dy));
        atomicAdd(&aggA[s & 63], atan2f(dy, dx));
      }
    }
  }
  __syncthreads();
  if (t < 64) baseD[t] = atomicAdd(&cntd[r * 64 + t], min(cD[t], PCAP));
  __syncthreads();
  for (int idx = t; idx < 64 * PCAP; idx += 256) {
    int n = idx >> 5;   // PCAP == 32
    int i = idx & 31;
    if (i < min(cD[n], PCAP)) esrcB[(r * 64 + n) * CAP + baseD[n] + i] = bufD[n][i];
  }
  if (t < 64) {
    atomicAdd(&agg[2 * (r * 64 + t)], aggD[t]);
    atomicAdd(&agg[2 * (r * 64 + t) + 1], aggA[t]);
  }
}

// ---------- layer-1 GEMM: 4 nodes/block, fused concat + alpha epilogue ----------
__global__ void k_gemm1(const float* __restrict__ x, const float* __restrict__ agg,
                        const float* __restrict__ W, const float* __restrict__ a_src,
                        const float* __restrict__ a_dst,
                        __half* __restrict__ Hout, float* __restrict__ asb,
                        float* __restrict__ adb) {
  __shared__ float xrow[4][64];
  int n0 = blockIdx.x * 4, t = threadIdx.x;
  int m0 = t >> 6, i0 = t & 63;
  xrow[m0][i0] = (i0 < FIN) ? x[(n0 + m0) * FIN + i0] : agg[(n0 + m0) * 2 + (i0 - FIN)];
  __syncthreads();
  float a0 = 0.f, a1 = 0.f, a2 = 0.f, a3 = 0.f;
#pragma unroll 8
  for (int k = 0; k < 64; ++k) {
    float w = W[k * HC + t];
    a0 += xrow[0][k] * w; a1 += xrow[1][k] * w;
    a2 += xrow[2][k] * w; a3 += xrow[3][k] * w;
  }
  Hout[(n0 + 0) * HC + t] = __float2half(a0);
  Hout[(n0 + 1) * HC + t] = __float2half(a1);
  Hout[(n0 + 2) * HC + t] = __float2half(a2);
  Hout[(n0 + 3) * HC + t] = __float2half(a3);
  float accs[4] = {a0, a1, a2, a3};
  int h = t >> 6, lane = t & 63;
  float vs = a_src[t], vdd = a_dst[t];
#pragma unroll
  for (int m = 0; m < 4; ++m) {
    float p1 = accs[m] * vs;
    float p2 = accs[m] * vdd;
    for (int o = 32; o > 0; o >>= 1) {
      p1 += __shfl_down(p1, o);
      p2 += __shfl_down(p2, o);
    }
    if (lane == 0) {
      asb[(n0 + m) * 4 + h] = p1;
      adb[(n0 + m) * 4 + h] = p2;
    }
  }
}

// ---------- layer-2 GEMM: 4 nodes/block, fused BN1+ReLU + alpha epilogue ----------
__global__ void k_gemm2(const __half* __restrict__ X, const float* __restrict__ mu,
                        const float* __restrict__ rinv, const float* __restrict__ g,
                        const float* __restrict__ be, const float* __restrict__ W,
                        const float* __restrict__ a_src, const float* __restrict__ a_dst,
                        __half* __restrict__ Hout, float* __restrict__ asb,
                        float* __restrict__ adb) {
  __shared__ float xrow[4][256];
  int n0 = blockIdx.x * 4, t = threadIdx.x;
  float bmu = mu[t], brv = rinv[t], bg = g[t], bb = be[t];
#pragma unroll
  for (int m = 0; m < 4; ++m)
    xrow[m][t] = fmaxf((ldh(X, (n0 + m) * HC + t) - bmu) * brv * bg + bb, 0.f);
  __syncthreads();
  float a0 = 0.f, a1 = 0.f, a2 = 0.f, a3 = 0.f;
#pragma unroll 4
  for (int k = 0; k < 256; ++k) {
    float w = W[k * HC + t];
    a0 += xrow[0][k] * w; a1 += xrow[1][k] * w;
    a2 += xrow[2][k] * w; a3 += xrow[3][k] * w;
  }
  Hout[(n0 + 0) * HC + t] = __float2half(a0);
  Hout[(n0 + 1) * HC + t] = __float2half(a1);
  Hout[(n0 + 2) * HC + t] = __float2half(a2);
  Hout[(n0 + 3) * HC + t] = __float2half(a3);
  float accs[4] = {a0, a1, a2, a3};
  int h = t >> 6, lane = t & 63;
  float vs = a_src[t], vdd = a_dst[t];
#pragma unroll
  for (int m = 0; m < 4; ++m) {
    float p1 = accs[m] * vs;
    float p2 = accs[m] * vdd;
    for (int o = 32; o > 0; o >>= 1) {
      p1 += __shfl_down(p1, o);
      p2 += __shfl_down(p2, o);
    }
    if (lane == 0) {
      asb[(n0 + m) * 4 + h] = p1;
      adb[(n0 + m) * 4 + h] = p2;
    }
  }
}

// ---------- GAT aggregate per dst node: bucket CSR, single chunk (cnt <= 240) ----------
__global__ void k_agg(const int* __restrict__ cntd, const u16* __restrict__ esrcB,
                      const float* __restrict__ asb, const float* __restrict__ adb,
                      const __half* __restrict__ Hin, const float* __restrict__ bias,
                      __half* __restrict__ Out) {
  __shared__ float eE[4][256];
  __shared__ int sS[256];
  __shared__ float wred[4][4];
  int n = blockIdx.x, t = threadIdx.x;
  int h = t >> 6, lane = t & 63;
  int cnt = min(cntd[n], CAP);

  float ad0 = adb[n * 4 + 0], ad1 = adb[n * 4 + 1];
  float ad2 = adb[n * 4 + 2], ad3 = adb[n * 4 + 3];

  float e0 = 0.f, e1 = 0.f, e2 = 0.f, e3 = 0.f;
  int s = 0;
  if (t < cnt) {
    s = (int)esrcB[n * CAP + t];
    e0 = expf(lrelu(asb[s * 4 + 0] + ad0));
    e1 = expf(lrelu(asb[s * 4 + 1] + ad1));
    e2 = expf(lrelu(asb[s * 4 + 2] + ad2));
    e3 = expf(lrelu(asb[s * 4 + 3] + ad3));
  }
  eE[0][t] = e0; eE[1][t] = e1; eE[2][t] = e2; eE[3][t] = e3;
  sS[t] = s;
  __syncthreads();

  float acc = 0.f;
#pragma unroll 4
  for (int j = 0; j < cnt; ++j) {
    acc += eE[h][j] * ldh(Hin, sS[j] * HC + t);
  }

  float d0 = e0, d1 = e1, d2 = e2, d3 = e3;
  for (int o = 32; o > 0; o >>= 1) {
    d0 += __shfl_down(d0, o);
    d1 += __shfl_down(d1, o);
    d2 += __shfl_down(d2, o);
    d3 += __shfl_down(d3, o);
  }
  if (lane == 0) {
    wred[h][0] = d0; wred[h][1] = d1; wred[h][2] = d2; wred[h][3] = d3;
  }
  __syncthreads();
  float denom = wred[0][h] + wred[1][h] + wred[2][h] + wred[3][h];
  Out[n * HC + t] = __float2half(acc / (denom + 1e-16f) + bias[t]);
}

// ---------- BN stats ----------
__global__ void k_bnstats(const __half* __restrict__ X, float* __restrict__ mu,
                          float* __restrict__ rinv) {
  __shared__ float rs[256];
  __shared__ float rq[256];
  int f = blockIdx.x, t = threadIdx.x;
  float s = 0.f, sq = 0.f;
  for (int n = t; n < NN; n += 256) {
    float v = ldh(X, n * HC + f);
    s += v;
    sq += v * v;
  }
  rs[t] = s; rq[t] = sq;
  __syncthreads();
  for (int o = 128; o > 0; o >>= 1) {
    if (t < o) { rs[t] += rs[t + o]; rq[t] += rq[t + o]; }
    __syncthreads();
  }
  if (t == 0) {
    float m = rs[0] / NN;
    float var = rq[0] / NN - m * m;
    mu[f] = m;
    rinv[f] = rsqrtf(var + 1e-5f);
  }
}

// ---------- final linear (fused BN2+ReLU) + mask + updated_pos ----------
__global__ void k_final(const __half* __restrict__ X, const float* __restrict__ mu,
                        const float* __restrict__ rinv, const float* __restrict__ g,
                        const float* __restrict__ be, const float* __restrict__ Wf,
                        const float* __restrict__ bfv, const float* __restrict__ mask,
                        const float* __restrict__ pos, float* __restrict__ out) {
  int n = blockIdx.x, l = threadIdx.x;  // 64 threads
  float r0 = 0.f, r1 = 0.f;
  for (int c = l; c < HC; c += 64) {
    float v = fmaxf((ldh(X, n * HC + c) - mu[c]) * rinv[c] * g[c] + be[c], 0.f);
    r0 += v * Wf[c * 2];
    r1 += v * Wf[c * 2 + 1];
  }
  for (int o = 32; o > 0; o >>= 1) {
    r0 += __shfl_down(r0, o);
    r1 += __shfl_down(r1, o);
  }
  if (l == 0) {
    float mk = mask[n];
    float o0 = (r0 + bfv[0]) * mk;
    float o1 = (r1 + bfv[1]) * mk;
    out[n * 2]     = o0;
    out[n * 2 + 1] = o1;
    out[2 * NN + n * 2]     = pos[n * 2]     + o0;
    out[2 * NN + n * 2 + 1] = pos[n * 2 + 1] + o1;
  }
}

extern "C" void kernel_launch(void* const* d_in, const int* in_sizes, int n_in,
                              void* d_out, int out_size, void* d_ws, size_t ws_size,
                              hipStream_t stream) {
  (void)in_sizes; (void)n_in; (void)out_size; (void)ws_size;
  const float* x    = (const float*)d_in[0];
  const int*   ei   = (const int*)d_in[1];
  const float* pos  = (const float*)d_in[2];
  const float* mask = (const float*)d_in[3];
  // d_in[4] = batch (int32), unused
  const float* W1   = (const float*)d_in[5];
  const float* as1  = (const float*)d_in[6];
  const float* ad1  = (const float*)d_in[7];
  const float* b1   = (const float*)d_in[8];
  const float* g1   = (const float*)d_in[9];
  const float* be1  = (const float*)d_in[10];
  const float* W2   = (const float*)d_in[11];
  const float* as2  = (const float*)d_in[12];
  const float* ad2  = (const float*)d_in[13];
  const float* b2   = (const float*)d_in[14];
  const float* g2   = (const float*)d_in[15];
  const float* be2  = (const float*)d_in[16];
  const float* Wf   = (const float*)d_in[17];
  const float* bfv  = (const float*)d_in[18];

  const int* srcp = ei;
  const int* dstp = ei + EE;

  // ws layout — ~3.93 MB (proven ws_size >= 4,077,568 B):
  //  agg f32[5120] asb[10240] adb[10240] mu[256] rinv[256] cntd int[2560]
  //  esrcB u16[2560*240] | o __half[655360] | h __half[655360]
  float* ws   = (float*)d_ws;
  float* agg  = ws;
  float* asb  = agg + 5120;
  float* adb  = asb + 10240;
  float* mu   = adb + 10240;
  float* rinv = mu + 256;
  int* cntd   = (int*)(rinv + 256);
  u16* esrcB  = (u16*)(cntd + 2560);
  __half* o   = (__half*)(esrcB + 2560 * CAP);
  __half* h   = o + 655360;

  k_init<<<(NN + 255) / 256, 256, 0, stream>>>(cntd, esrcB, agg);
  dim3 grid_bin(NCH, NN / 64);
  k_bin<<<grid_bin, 256, 0, stream>>>(srcp, dstp, pos, cntd, esrcB, agg);

  // ---- layer 1 ----
  k_gemm1<<<NN / 4, 256, 0, stream>>>(x, agg, W1, as1, ad1, h, asb, adb);
  k_agg<<<NN, 256, 0, stream>>>(cntd, esrcB, asb, adb, h, b1, o);
  k_bnstats<<<HC, 256, 0, stream>>>(o, mu, rinv);

  // ---- layer 2 (BN1 fused into gemm2 load) ----
  k_gemm2<<<NN / 4, 256, 0, stream>>>(o, mu, rinv, g1, be1, W2, as2, ad2, h, asb, adb);
  k_agg<<<NN, 256, 0, stream>>>(cntd, esrcB, asb, adb, h, b2, o);
  k_bnstats<<<HC, 256, 0, stream>>>(o, mu, rinv);

  // ---- final (BN2 fused) ----
  k_final<<<NN, 64, 0, stream>>>(o, mu, rinv, g2, be2, Wf, bfv, mask, pos, (float*)d_out);
}